// Round 1
// baseline (95.099 us; speedup 1.0000x reference)
//
#include <hip/hip_runtime.h>
#include <math.h>

#define NW 8
#define DIM 256

// One wave (64 lanes) simulates one batch item; each lane holds 4 complex
// amplitudes (n = lane*4 + j). Wire i acts on basis-bit (7-i):
//   wires 0..5 -> cross-lane shfl_xor with mask 32..1
//   wires 6,7  -> in-lane pairs (0,2)/(1,3) and (0,1)/(2,3)
__global__ __launch_bounds__(256) void vqc_kernel(
    const float* __restrict__ x,     // [B,8] encoder angles
    const float* __restrict__ ry1,   // [8]
    const float* __restrict__ crz1,  // [8]
    const float* __restrict__ ry2,   // [8]
    const float* __restrict__ crz2,  // [8]
    float* __restrict__ out,         // [B,8]
    int B)
{
    // CRZ diagonal phase tables (fixed per launch), float4-aligned for b128 reads
    __shared__ float4 pc1[DIM / 4], ps1[DIM / 4], pc2[DIM / 4], ps2[DIM / 4];

    const int t = threadIdx.x;
    {
        // basis state n = t; expo = sum_i bit_ctrl * theta_i * (bit_tgt - 0.5)
        float e1 = 0.f, e2 = 0.f;
#pragma unroll
        for (int i = 0; i < NW; ++i) {
            float bc  = (float)((t >> (7 - i)) & 1);
            float bt1 = (float)((t >> (7 - ((i + 1) & 7))) & 1);
            float bt2 = (float)((t >> (7 - ((i + 7) & 7))) & 1);
            e1 += bc * crz1[i] * (bt1 - 0.5f);
            e2 += bc * crz2[i] * (bt2 - 0.5f);
        }
        float s, c;
        __sincosf(e1, &s, &c);
        ((float*)pc1)[t] = c; ((float*)ps1)[t] = s;
        __sincosf(e2, &s, &c);
        ((float*)pc2)[t] = c; ((float*)ps2)[t] = s;
    }
    __syncthreads();

    const int lane = t & 63;
    const int wv   = t >> 6;
    const int wavesPerBlock = blockDim.x >> 6;
    const int gw = blockIdx.x * wavesPerBlock + wv;
    const int TW = gridDim.x * wavesPerBlock;

    // shared RY params: lane w computes cos/sin(theta_w/2); broadcast via shfl
    float rc1v, rs1v, rc2v, rs2v;
    __sincosf(0.5f * ry1[lane & 7], &rs1v, &rc1v);
    __sincosf(0.5f * ry2[lane & 7], &rs2v, &rc2v);

    // this lane's 4 phase-table entries
    const float4 c1 = pc1[lane], s1 = ps1[lane];
    const float4 c2 = pc2[lane], s2 = ps2[lane];

#define RY_LAYER(RCV, RSV)                                                  \
    do {                                                                    \
        _Pragma("unroll")                                                   \
        for (int i = 0; i < 6; ++i) {                                       \
            float c = __shfl(RCV, i);                                       \
            float s = __shfl(RSV, i);                                       \
            int mask = 1 << (5 - i);                                        \
            float se = ((lane >> (5 - i)) & 1) ? s : -s;                    \
            _Pragma("unroll")                                               \
            for (int j = 0; j < 4; ++j) {                                   \
                float pre = __shfl_xor(re[j], mask);                        \
                float pim = __shfl_xor(im[j], mask);                        \
                re[j] = fmaf(se, pre, c * re[j]);                           \
                im[j] = fmaf(se, pim, c * im[j]);                           \
            }                                                               \
        }                                                                   \
        {   /* wire 6: bit1 of j -> pairs (0,2),(1,3) */                    \
            float c = __shfl(RCV, 6), s = __shfl(RSV, 6);                   \
            float nr0 = c * re[0] - s * re[2], nr2 = fmaf(s, re[0], c * re[2]); \
            float nr1 = c * re[1] - s * re[3], nr3 = fmaf(s, re[1], c * re[3]); \
            float ni0 = c * im[0] - s * im[2], ni2 = fmaf(s, im[0], c * im[2]); \
            float ni1 = c * im[1] - s * im[3], ni3 = fmaf(s, im[1], c * im[3]); \
            re[0] = nr0; re[1] = nr1; re[2] = nr2; re[3] = nr3;             \
            im[0] = ni0; im[1] = ni1; im[2] = ni2; im[3] = ni3;             \
        }                                                                   \
        {   /* wire 7: bit0 of j -> pairs (0,1),(2,3) */                    \
            float c = __shfl(RCV, 7), s = __shfl(RSV, 7);                   \
            float nr0 = c * re[0] - s * re[1], nr1 = fmaf(s, re[0], c * re[1]); \
            float nr2 = c * re[2] - s * re[3], nr3 = fmaf(s, re[2], c * re[3]); \
            float ni0 = c * im[0] - s * im[1], ni1 = fmaf(s, im[0], c * im[1]); \
            float ni2 = c * im[2] - s * im[3], ni3 = fmaf(s, im[2], c * im[3]); \
            re[0] = nr0; re[1] = nr1; re[2] = nr2; re[3] = nr3;             \
            im[0] = ni0; im[1] = ni1; im[2] = ni2; im[3] = ni3;             \
        }                                                                   \
    } while (0)

    for (int b = gw; b < B; b += TW) {
        // ---- encoding: product state. lane w (w<8) computes cos/sin(x_w/2)
        float h = 0.5f * x[(size_t)b * NW + (lane & 7)];
        float cv, sv;
        __sincosf(h, &sv, &cv);
        float prod = 1.f;
#pragma unroll
        for (int w = 0; w < 6; ++w) {
            float cw = __shfl(cv, w);
            float sw = __shfl(sv, w);
            prod *= ((lane >> (5 - w)) & 1) ? sw : cw;
        }
        float c6 = __shfl(cv, 6), s6 = __shfl(sv, 6);
        float c7 = __shfl(cv, 7), s7 = __shfl(sv, 7);
        float a0 = prod * c6 * c7;
        float a1 = prod * c6 * s7;
        float a2 = prod * s6 * c7;
        float a3 = prod * s6 * s7;

        // ---- CRZ block 1 on a real state: re = a*cos, im = a*sin
        float re[4], im[4];
        re[0] = a0 * c1.x; im[0] = a0 * s1.x;
        re[1] = a1 * c1.y; im[1] = a1 * s1.y;
        re[2] = a2 * c1.z; im[2] = a2 * s1.z;
        re[3] = a3 * c1.w; im[3] = a3 * s1.w;

        // ---- RY layer (params_ry1)
        RY_LAYER(rc1v, rs1v);

        // ---- CRZ block 2: full complex multiply by (c2, s2)
        {
            float nr, ni;
            nr = re[0] * c2.x - im[0] * s2.x; ni = re[0] * s2.x + im[0] * c2.x; re[0] = nr; im[0] = ni;
            nr = re[1] * c2.y - im[1] * s2.y; ni = re[1] * s2.y + im[1] * c2.y; re[1] = nr; im[1] = ni;
            nr = re[2] * c2.z - im[2] * s2.z; ni = re[2] * s2.z + im[2] * c2.z; re[2] = nr; im[2] = ni;
            nr = re[3] * c2.w - im[3] * s2.w; ni = re[3] * s2.w + im[3] * c2.w; re[3] = nr; im[3] = ni;
        }

        // ---- RY layer (params_ry2)
        RY_LAYER(rc2v, rs2v);

        // ---- probabilities and per-wire Z expectations
        float p0 = re[0] * re[0] + im[0] * im[0];
        float p1 = re[1] * re[1] + im[1] * im[1];
        float p2 = re[2] * re[2] + im[2] * im[2];
        float p3 = re[3] * re[3] + im[3] * im[3];
        float psum = (p0 + p1) + (p2 + p3);

        float tt[8];
#pragma unroll
        for (int w = 0; w < 6; ++w)
            tt[w] = ((lane >> (5 - w)) & 1) ? -psum : psum;
        tt[6] = (p0 + p1) - (p2 + p3);
        tt[7] = (p0 - p1) + (p2 - p3);

#pragma unroll
        for (int off = 32; off > 0; off >>= 1) {
#pragma unroll
            for (int w = 0; w < 8; ++w)
                tt[w] += __shfl_xor(tt[w], off);
        }

        if (lane == 0) {
            float4* op = (float4*)(out + (size_t)b * NW);
            op[0] = make_float4(tt[0], tt[1], tt[2], tt[3]);
            op[1] = make_float4(tt[4], tt[5], tt[6], tt[7]);
        }
    }
#undef RY_LAYER
}

extern "C" void kernel_launch(void* const* d_in, const int* in_sizes, int n_in,
                              void* d_out, int out_size, void* d_ws, size_t ws_size,
                              hipStream_t stream) {
    const float* x    = (const float*)d_in[0];
    const float* ry1  = (const float*)d_in[1];
    const float* crz1 = (const float*)d_in[2];
    const float* ry2  = (const float*)d_in[3];
    const float* crz2 = (const float*)d_in[4];
    float* out = (float*)d_out;

    int B = in_sizes[0] / NW;                 // 16384
    // 4 waves/block, ~4 items per wave -> 1024 blocks (4 blocks/CU on 256 CUs)
    int waves_needed = (B + 3) / 4;
    int blocks = (waves_needed + 3) / 4;
    if (blocks < 1) blocks = 1;
    vqc_kernel<<<blocks, 256, 0, stream>>>(x, ry1, crz1, ry2, crz2, out, B);
}

// Round 2
// 82.011 us; speedup vs baseline: 1.1596x; 1.1596x over previous
//
#include <hip/hip_runtime.h>
#include <math.h>

#define NW 8
#define DIM 256

// One wave (64 lanes) = one batch item; each lane holds 4 complex amplitudes
// (n = lane*4 + j). Wire i acts on basis-bit (7-i):
//   wires 0..5 -> cross-lane shfl_xor with mask 32..1
//   wires 6,7  -> in-lane pairs (0,2)/(1,3) and (0,1)/(2,3)
// Readout uses a Walsh-Hadamard butterfly: wire w (w<6) expectation is the
// Walsh coefficient of psum at lane index 1<<(5-w).
__global__ __launch_bounds__(256) void vqc_kernel(
    const float* __restrict__ x,     // [B,8] encoder angles
    const float* __restrict__ ry1,   // [8]
    const float* __restrict__ crz1,  // [8]
    const float* __restrict__ ry2,   // [8]
    const float* __restrict__ crz2,  // [8]
    float* __restrict__ out,         // [B,8]
    int B)
{
    // CRZ diagonal phase tables (param-only), float4-aligned
    __shared__ float4 pc1[DIM / 4], ps1[DIM / 4], pc2[DIM / 4], ps2[DIM / 4];

    const int t = threadIdx.x;
    {
        float e1 = 0.f, e2 = 0.f;
#pragma unroll
        for (int i = 0; i < NW; ++i) {
            float bc  = (float)((t >> (7 - i)) & 1);
            float bt1 = (float)((t >> (7 - ((i + 1) & 7))) & 1);
            float bt2 = (float)((t >> (7 - ((i + 7) & 7))) & 1);
            e1 += bc * crz1[i] * (bt1 - 0.5f);
            e2 += bc * crz2[i] * (bt2 - 0.5f);
        }
        float s, c;
        __sincosf(e1, &s, &c);
        ((float*)pc1)[t] = c; ((float*)ps1)[t] = s;
        __sincosf(e2, &s, &c);
        ((float*)pc2)[t] = c; ((float*)ps2)[t] = s;
    }
    __syncthreads();

    const int lane = t & 63;

    // Shared RY params: every lane computes all 8 cos/sin pairs per layer
    // directly (uniform s_load + VALU sincos) -- no DS-pipe broadcasts.
    float rc1[8], rs1[8], rc2[8], rs2[8];
#pragma unroll
    for (int i = 0; i < 8; ++i) {
        __sincosf(0.5f * ry1[i], &rs1[i], &rc1[i]);
        __sincosf(0.5f * ry2[i], &rs2[i], &rc2[i]);
    }

    // This lane's 4 phase-table entries (loop-invariant)
    const float4 c1 = pc1[lane], s1 = ps1[lane];
    const float4 c2 = pc2[lane], s2 = ps2[lane];

    const int wavesPerBlock = blockDim.x >> 6;
    int gw = blockIdx.x * wavesPerBlock + (t >> 6);
    const int TW = gridDim.x * wavesPerBlock;

#define RY_LAYER(RC, RS)                                                    \
    do {                                                                    \
        _Pragma("unroll")                                                   \
        for (int i = 0; i < 6; ++i) {                                       \
            float c = RC[i], s = RS[i];                                     \
            const int mask = 1 << (5 - i);                                  \
            float se = (lane & mask) ? s : -s;                              \
            _Pragma("unroll")                                               \
            for (int j = 0; j < 4; ++j) {                                   \
                float pre = __shfl_xor(re[j], mask);                        \
                float pim = __shfl_xor(im[j], mask);                        \
                re[j] = fmaf(se, pre, c * re[j]);                           \
                im[j] = fmaf(se, pim, c * im[j]);                           \
            }                                                               \
        }                                                                   \
        {   /* wire 6: bit1 of j -> pairs (0,2),(1,3) */                    \
            float c = RC[6], s = RS[6];                                     \
            float nr0 = c * re[0] - s * re[2], nr2 = fmaf(s, re[0], c * re[2]); \
            float nr1 = c * re[1] - s * re[3], nr3 = fmaf(s, re[1], c * re[3]); \
            float ni0 = c * im[0] - s * im[2], ni2 = fmaf(s, im[0], c * im[2]); \
            float ni1 = c * im[1] - s * im[3], ni3 = fmaf(s, im[1], c * im[3]); \
            re[0] = nr0; re[1] = nr1; re[2] = nr2; re[3] = nr3;             \
            im[0] = ni0; im[1] = ni1; im[2] = ni2; im[3] = ni3;             \
        }                                                                   \
        {   /* wire 7: bit0 of j -> pairs (0,1),(2,3) */                    \
            float c = RC[7], s = RS[7];                                     \
            float nr0 = c * re[0] - s * re[1], nr1 = fmaf(s, re[0], c * re[1]); \
            float nr2 = c * re[2] - s * re[3], nr3 = fmaf(s, re[2], c * re[3]); \
            float ni0 = c * im[0] - s * im[1], ni1 = fmaf(s, im[0], c * im[1]); \
            float ni2 = c * im[2] - s * im[3], ni3 = fmaf(s, im[2], c * im[3]); \
            re[0] = nr0; re[1] = nr1; re[2] = nr2; re[3] = nr3;             \
            im[0] = ni0; im[1] = ni1; im[2] = ni2; im[3] = ni3;             \
        }                                                                   \
    } while (0)

    for (int b = gw; b < B; b += TW) {
        // ---- encoding: every lane loads all 8 angles (one item per wave;
        // both float4 loads hit the same 32B line) and computes 8 sincos.
        const float4* xp = (const float4*)(x + (size_t)b * NW);
        float4 xa = xp[0], xb = xp[1];
        float cs[8], sn[8];
        __sincosf(0.5f * xa.x, &sn[0], &cs[0]);
        __sincosf(0.5f * xa.y, &sn[1], &cs[1]);
        __sincosf(0.5f * xa.z, &sn[2], &cs[2]);
        __sincosf(0.5f * xa.w, &sn[3], &cs[3]);
        __sincosf(0.5f * xb.x, &sn[4], &cs[4]);
        __sincosf(0.5f * xb.y, &sn[5], &cs[5]);
        __sincosf(0.5f * xb.z, &sn[6], &cs[6]);
        __sincosf(0.5f * xb.w, &sn[7], &cs[7]);

        float pr = 1.f;
        pr *= (lane & 32) ? sn[0] : cs[0];
        pr *= (lane & 16) ? sn[1] : cs[1];
        pr *= (lane & 8)  ? sn[2] : cs[2];
        pr *= (lane & 4)  ? sn[3] : cs[3];
        pr *= (lane & 2)  ? sn[4] : cs[4];
        pr *= (lane & 1)  ? sn[5] : cs[5];
        float a0 = pr * cs[6] * cs[7];
        float a1 = pr * cs[6] * sn[7];
        float a2 = pr * sn[6] * cs[7];
        float a3 = pr * sn[6] * sn[7];

        // ---- CRZ block 1 on a real state: re = a*cos, im = a*sin
        float re[4], im[4];
        re[0] = a0 * c1.x; im[0] = a0 * s1.x;
        re[1] = a1 * c1.y; im[1] = a1 * s1.y;
        re[2] = a2 * c1.z; im[2] = a2 * s1.z;
        re[3] = a3 * c1.w; im[3] = a3 * s1.w;

        // ---- RY layer (params_ry1)
        RY_LAYER(rc1, rs1);

        // ---- CRZ block 2: full complex multiply by (c2, s2)
        {
            float nr, ni;
            nr = re[0] * c2.x - im[0] * s2.x; ni = re[0] * s2.x + im[0] * c2.x; re[0] = nr; im[0] = ni;
            nr = re[1] * c2.y - im[1] * s2.y; ni = re[1] * s2.y + im[1] * c2.y; re[1] = nr; im[1] = ni;
            nr = re[2] * c2.z - im[2] * s2.z; ni = re[2] * s2.z + im[2] * c2.z; re[2] = nr; im[2] = ni;
            nr = re[3] * c2.w - im[3] * s2.w; ni = re[3] * s2.w + im[3] * c2.w; re[3] = nr; im[3] = ni;
        }

        // ---- RY layer (params_ry2)
        RY_LAYER(rc2, rs2);

        // ---- probabilities and per-wire Z expectations
        float p0 = re[0] * re[0] + im[0] * im[0];
        float p1 = re[1] * re[1] + im[1] * im[1];
        float p2 = re[2] * re[2] + im[2] * im[2];
        float p3 = re[3] * re[3] + im[3] * im[3];

        float v0 = (p0 + p1) + (p2 + p3);          // psum -> Walsh butterfly
        float v6 = (p0 + p1) - (p2 + p3);          // wire 6 partial
        float v7 = (p0 - p1) + (p2 - p3);          // wire 7 partial

        // Walsh-Hadamard butterfly: after 6 rounds, lane L holds
        // sum_l (-1)^popcount(l&L) v_l. Wire w (w<6) result at lane 1<<(5-w);
        // plain sums (v6, v7) at lane 0.
#pragma unroll
        for (int m = 1; m <= 32; m <<= 1) {
            float o0 = __shfl_xor(v0, m);
            float o6 = __shfl_xor(v6, m);
            float o7 = __shfl_xor(v7, m);
            if (lane & m) { v0 = o0 - v0; v6 = o6 - v6; v7 = o7 - v7; }
            else          { v0 = o0 + v0; v6 = o6 + v6; v7 = o7 + v7; }
        }

        float* ob = out + (size_t)b * NW;
        if (lane == 0) {
            ob[6] = v6;
            ob[7] = v7;
        } else {
            int k = __ffs(lane) - 1;                 // lane == 1<<k ?
            if (lane == (1 << k) && k <= 5)
                ob[5 - k] = v0;                      // wire w = 5-k
        }
    }
#undef RY_LAYER
}

extern "C" void kernel_launch(void* const* d_in, const int* in_sizes, int n_in,
                              void* d_out, int out_size, void* d_ws, size_t ws_size,
                              hipStream_t stream) {
    const float* x    = (const float*)d_in[0];
    const float* ry1  = (const float*)d_in[1];
    const float* crz1 = (const float*)d_in[2];
    const float* ry2  = (const float*)d_in[3];
    const float* crz2 = (const float*)d_in[4];
    float* out = (float*)d_out;

    int B = in_sizes[0] / NW;                 // 16384
    // one item per wave, 4 waves per block -> 4096 blocks
    int blocks = (B + 3) / 4;
    if (blocks < 1) blocks = 1;
    vqc_kernel<<<blocks, 256, 0, stream>>>(x, ry1, crz1, ry2, crz2, out, B);
}

// Round 3
// 71.377 us; speedup vs baseline: 1.3323x; 1.1490x over previous
//
#include <hip/hip_runtime.h>
#include <math.h>

#define NW 8

// ---- cross-lane exchange helpers -------------------------------------------
// XOR1/XOR2 via DPP quad_perm, XOR8 via DPP row_ror:8 (rotate by half a 16-row
// == XOR8), XOR4 via ds_swizzle (only DS-pipe exchange left).
template<int CTRL>
__device__ __forceinline__ float dpp_x(float v) {
    return __int_as_float(
        __builtin_amdgcn_update_dpp(0, __float_as_int(v), CTRL, 0xF, 0xF, true));
}
__device__ __forceinline__ float swz_xor4(float v) {
    return __int_as_float(__builtin_amdgcn_ds_swizzle(__float_as_int(v), 0x101F));
}
#define XCH1(v) dpp_x<0xB1>(v)   /* quad_perm [1,0,3,2] */
#define XCH2(v) dpp_x<0x4E>(v)   /* quad_perm [2,3,0,1] */
#define XCH8(v) dpp_x<0x128>(v)  /* row_ror:8           */
#define XCH4(v) swz_xor4(v)

// Layout: wave = 4 items (group g = lane>>4), sublane sl = lane&15 holds 16
// amplitudes n = nh(sl)*16 + j, where the n-highbits <-> lane-bit map is:
//   n bit7 <-> sl bit0 (XOR1/DPP), bit6 <-> sl bit1 (XOR2/DPP),
//   n bit5 <-> sl bit3 (XOR8/DPP), bit4 <-> sl bit2 (XOR4/ds_swizzle)
// n bits 3..0 = j (in-lane). Wire i acts on n bit (7-i).
__global__ __launch_bounds__(256) void vqc_kernel(
    const float* __restrict__ x,     // [B,8]
    const float* __restrict__ ry1,   // [8]
    const float* __restrict__ crz1,  // [8]
    const float* __restrict__ ry2,   // [8]
    const float* __restrict__ crz2,  // [8]
    float* __restrict__ out,         // [B,8]
    int B)
{
    // CRZ phase tables, sl-permuted, rows padded 16->20 floats (80B, still
    // 16B-aligned for b128; 20*sl mod 32 gives only 2-way bank aliasing = free)
    __shared__ __align__(16) float Tc1[320], Ts1[320], Tc2[320], Ts2[320];

    const int t = threadIdx.x;
    {
        const int n = t;  // basis index 0..255
        float e1 = 0.f, e2 = 0.f;
#pragma unroll
        for (int i = 0; i < NW; ++i) {
            float bc  = (float)((n >> (7 - i)) & 1);
            float bt1 = (float)((n >> (7 - ((i + 1) & 7))) & 1);
            float bt2 = (float)((n >> (7 - ((i + 7) & 7))) & 1);
            e1 += bc * crz1[i] * (bt1 - 0.5f);
            e2 += bc * crz2[i] * (bt2 - 0.5f);
        }
        const int j  = n & 15;
        const int nh = n >> 4;
        // inverse of nh(sl): nh bit3->sl bit0, bit2->sl bit1, bit0->sl bit2, bit1->sl bit3
        const int sl = ((nh >> 3) & 1) | (((nh >> 2) & 1) << 1)
                     | ((nh & 1) << 2) | (((nh >> 1) & 1) << 3);
        const int idx = sl * 20 + j;
        float s, c;
        __sincosf(e1, &s, &c);  Tc1[idx] = c;  Ts1[idx] = s;
        __sincosf(e2, &s, &c);  Tc2[idx] = c;  Ts2[idx] = s;
    }
    __syncthreads();

    const int lane = t & 63;
    const int sl   = lane & 15;
    const int g    = lane >> 4;

    // shared RY params: computed by every lane (VALU is cheap here)
    float rc1[8], rs1[8], rc2[8], rs2[8];
#pragma unroll
    for (int i = 0; i < 8; ++i) {
        __sincosf(0.5f * ry1[i], &rs1[i], &rc1[i]);
        __sincosf(0.5f * ry2[i], &rs2[i], &rc2[i]);
    }

    const float* pc1 = &Tc1[sl * 20];
    const float* ps1 = &Ts1[sl * 20];
    const float* pc2 = &Tc2[sl * 20];
    const float* ps2 = &Ts2[sl * 20];

    const int wavesPerBlock = blockDim.x >> 6;
    const int gwave = blockIdx.x * wavesPerBlock + (t >> 6);
    const int TW = gridDim.x * wavesPerBlock;

#define CROSS_WIRE(RC, RS, WI, SLBIT, EXCH)                                 \
    { float c = RC[WI], s = RS[WI];                                         \
      float se = (sl & SLBIT) ? s : -s;                                     \
      _Pragma("unroll")                                                     \
      for (int j = 0; j < 16; ++j) {                                        \
          float pre = EXCH(re[j]);                                          \
          float pim = EXCH(im[j]);                                          \
          re[j] = fmaf(se, pre, c * re[j]);                                 \
          im[j] = fmaf(se, pim, c * im[j]);                                 \
      } }

#define INLANE_WIRE(RC, RS, WI, M)                                          \
    { float c = RC[WI], s = RS[WI];                                         \
      _Pragma("unroll")                                                     \
      for (int j = 0; j < 16; ++j) if (!(j & M)) {                          \
          int hi = j | M;                                                   \
          float rl = re[j], rh = re[hi], il = im[j], ih = im[hi];           \
          re[j]  = c * rl - s * rh;  re[hi] = fmaf(s, rl, c * rh);          \
          im[j]  = c * il - s * ih;  im[hi] = fmaf(s, il, c * ih);          \
      } }

#define RY_LAYER(RC, RS)                                                    \
    do {                                                                    \
        CROSS_WIRE(RC, RS, 0, 1, XCH1);                                     \
        CROSS_WIRE(RC, RS, 1, 2, XCH2);                                     \
        CROSS_WIRE(RC, RS, 2, 8, XCH8);                                     \
        CROSS_WIRE(RC, RS, 3, 4, XCH4);                                     \
        INLANE_WIRE(RC, RS, 4, 8);                                          \
        INLANE_WIRE(RC, RS, 5, 4);                                          \
        INLANE_WIRE(RC, RS, 6, 2);                                          \
        INLANE_WIRE(RC, RS, 7, 1);                                          \
    } while (0)

    for (int b0 = gwave * 4; b0 < B; b0 += TW * 4) {
        const int b  = b0 + g;
        const int bl = (b < B) ? b : (B - 1);

        // ---- encoding: this lane's item's 8 angles
        const float4* xp = (const float4*)(x + (size_t)bl * NW);
        float4 xa = xp[0], xb = xp[1];
        float cs[8], sn[8];
        __sincosf(0.5f * xa.x, &sn[0], &cs[0]);
        __sincosf(0.5f * xa.y, &sn[1], &cs[1]);
        __sincosf(0.5f * xa.z, &sn[2], &cs[2]);
        __sincosf(0.5f * xa.w, &sn[3], &cs[3]);
        __sincosf(0.5f * xb.x, &sn[4], &cs[4]);
        __sincosf(0.5f * xb.y, &sn[5], &cs[5]);
        __sincosf(0.5f * xb.z, &sn[6], &cs[6]);
        __sincosf(0.5f * xb.w, &sn[7], &cs[7]);

        // cross-lane factor (wires 0..3 per the lane-bit map)
        float pcf = ((sl & 1) ? sn[0] : cs[0])
                  * ((sl & 2) ? sn[1] : cs[1])
                  * ((sl & 8) ? sn[2] : cs[2])
                  * ((sl & 4) ? sn[3] : cs[3]);

        // in-lane products over j bits (wire4<->j&8 ... wire7<->j&1)
        float a[16];
#pragma unroll
        for (int j = 0; j < 16; ++j) {
            float f = ((j & 1) ? sn[7] : cs[7]);
            f *= ((j & 2) ? sn[6] : cs[6]);
            f *= ((j & 4) ? sn[5] : cs[5]);
            f *= ((j & 8) ? sn[4] : cs[4]);
            a[j] = pcf * f;
        }

        // ---- CRZ block 1 on real state: re = a*cos, im = a*sin
        float re[16], im[16];
#pragma unroll
        for (int q = 0; q < 4; ++q) {
            float4 cq = *(const float4*)&pc1[4 * q];
            float4 sq = *(const float4*)&ps1[4 * q];
            re[4*q+0] = a[4*q+0] * cq.x;  im[4*q+0] = a[4*q+0] * sq.x;
            re[4*q+1] = a[4*q+1] * cq.y;  im[4*q+1] = a[4*q+1] * sq.y;
            re[4*q+2] = a[4*q+2] * cq.z;  im[4*q+2] = a[4*q+2] * sq.z;
            re[4*q+3] = a[4*q+3] * cq.w;  im[4*q+3] = a[4*q+3] * sq.w;
        }

        // ---- RY layer 1
        RY_LAYER(rc1, rs1);

        // ---- CRZ block 2: complex multiply
#pragma unroll
        for (int q = 0; q < 4; ++q) {
            float4 cq = *(const float4*)&pc2[4 * q];
            float4 sq = *(const float4*)&ps2[4 * q];
            float nr, ni;
            nr = re[4*q+0]*cq.x - im[4*q+0]*sq.x; ni = re[4*q+0]*sq.x + im[4*q+0]*cq.x; re[4*q+0] = nr; im[4*q+0] = ni;
            nr = re[4*q+1]*cq.y - im[4*q+1]*sq.y; ni = re[4*q+1]*sq.y + im[4*q+1]*cq.y; re[4*q+1] = nr; im[4*q+1] = ni;
            nr = re[4*q+2]*cq.z - im[4*q+2]*sq.z; ni = re[4*q+2]*sq.z + im[4*q+2]*cq.z; re[4*q+2] = nr; im[4*q+2] = ni;
            nr = re[4*q+3]*cq.w - im[4*q+3]*sq.w; ni = re[4*q+3]*sq.w + im[4*q+3]*cq.w; re[4*q+3] = nr; im[4*q+3] = ni;
        }

        // ---- RY layer 2
        RY_LAYER(rc2, rs2);

        // ---- probabilities + in-lane Walsh partials over j bits
        float p[16];
#pragma unroll
        for (int j = 0; j < 16; ++j) p[j] = re[j]*re[j] + im[j]*im[j];

        float s2_[8], v7 = 0.f;
#pragma unroll
        for (int k = 0; k < 8; ++k) { s2_[k] = p[2*k] + p[2*k+1]; v7 += p[2*k] - p[2*k+1]; }
        float s4_[4], v6 = 0.f;
#pragma unroll
        for (int k = 0; k < 4; ++k) { s4_[k] = s2_[2*k] + s2_[2*k+1]; v6 += s2_[2*k] - s2_[2*k+1]; }
        float s8a = s4_[0] + s4_[1], s8b = s4_[2] + s4_[3];
        float v5 = (s4_[0] - s4_[1]) + (s4_[2] - s4_[3]);
        float v4 = s8a - s8b;
        float v0 = s8a + s8b;

        // ---- cross-lane Walsh butterfly (masks 1,2,4,8) on 5 values
#define BFLY_R(EXCH, M)                                                     \
        { float o0 = EXCH(v0), o4 = EXCH(v4), o5 = EXCH(v5),                \
                o6 = EXCH(v6), o7 = EXCH(v7);                               \
          if (sl & M) { v0 = o0 - v0; v4 = o4 - v4; v5 = o5 - v5;           \
                        v6 = o6 - v6; v7 = o7 - v7; }                       \
          else        { v0 = o0 + v0; v4 = o4 + v4; v5 = o5 + v5;           \
                        v6 = o6 + v6; v7 = o7 + v7; } }
        BFLY_R(XCH1, 1);
        BFLY_R(XCH2, 2);
        BFLY_R(XCH4, 4);
        BFLY_R(XCH8, 8);
#undef BFLY_R

        // wire0 sign-bit = sl&1 -> Walsh coeff at sl==1; wire1 -> sl==2;
        // wire2 -> sl==8; wire3 -> sl==4; plain sums (wires 4..7) at sl==0.
        if (b < B) {
            float* ob = out + (size_t)b * NW;
            if      (sl == 1) ob[0] = v0;
            else if (sl == 2) ob[1] = v0;
            else if (sl == 8) ob[2] = v0;
            else if (sl == 4) ob[3] = v0;
            else if (sl == 0) *(float4*)(ob + 4) = make_float4(v4, v5, v6, v7);
        }
    }
#undef RY_LAYER
#undef CROSS_WIRE
#undef INLANE_WIRE
}

extern "C" void kernel_launch(void* const* d_in, const int* in_sizes, int n_in,
                              void* d_out, int out_size, void* d_ws, size_t ws_size,
                              hipStream_t stream) {
    const float* x    = (const float*)d_in[0];
    const float* ry1  = (const float*)d_in[1];
    const float* crz1 = (const float*)d_in[2];
    const float* ry2  = (const float*)d_in[3];
    const float* crz2 = (const float*)d_in[4];
    float* out = (float*)d_out;

    int B = in_sizes[0] / NW;                  // 16384
    // 4 items/wave, 4 waves/block -> 16 items/block
    int blocks = (B + 15) / 16;
    if (blocks < 1) blocks = 1;
    vqc_kernel<<<blocks, 256, 0, stream>>>(x, ry1, crz1, ry2, crz2, out, B);
}

// Round 4
// 69.791 us; speedup vs baseline: 1.3626x; 1.0227x over previous
//
#include <hip/hip_runtime.h>
#include <math.h>

#define NW 8

// ---- cross-lane exchanges: all DPP (VALU pipe, no DS) ----------------------
template<int CTRL>
__device__ __forceinline__ float dpp_x(float v) {
    return __int_as_float(
        __builtin_amdgcn_update_dpp(0, __float_as_int(v), CTRL, 0xF, 0xF, true));
}
#define XCH1(v) dpp_x<0xB1>(v)   /* quad_perm [1,0,3,2]  == lane XOR 1 */
#define XCH2(v) dpp_x<0x4E>(v)   /* quad_perm [2,3,0,1]  == lane XOR 2 */
#define XCH8(v) dpp_x<0x128>(v)  /* row_ror:8 on 16-rows == lane XOR 8 */

// Layout: wave = 8 items. Item id g = lane bits {5,4,2}; amplitude sublane
// u = lane bits {0,1,3}. Each lane holds 32 amplitudes n = (u0<<7)|(u1<<6)|
// (u2<<5)|j  (u0=lane&1, u1=(lane>>1)&1, u2=(lane>>3)&1, j=n&31).
// Wire i acts on n-bit (7-i): wires 0,1,2 cross-lane (XOR1/XOR2/XOR8 DPP),
// wires 3..7 in-lane on j bits 4..0.
__global__ __launch_bounds__(256, 2) void vqc_kernel(
    const float* __restrict__ x,     // [B,8]
    const float* __restrict__ ry1,   // [8]
    const float* __restrict__ crz1,  // [8]
    const float* __restrict__ ry2,   // [8]
    const float* __restrict__ crz2,  // [8]
    float* __restrict__ out,         // [B,8]
    int B)
{
    // CRZ tables: 8 rows (one per u) x 32 floats, padded to 36 so the 8 rows
    // start on disjoint bank quads (4*u mod 32) -> conflict-free b128 reads;
    // 144B rows keep 16B alignment.
    __shared__ __align__(16) float Tc1[288], Ts1[288], Tc2[288], Ts2[288];

    const int t = threadIdx.x;
    {
        const int n = t;  // basis index 0..255
        float e1 = 0.f, e2 = 0.f;
#pragma unroll
        for (int i = 0; i < NW; ++i) {
            float bc  = (float)((n >> (7 - i)) & 1);
            float bt1 = (float)((n >> (7 - ((i + 1) & 7))) & 1);
            float bt2 = (float)((n >> (7 - ((i + 7) & 7))) & 1);
            e1 += bc * crz1[i] * (bt1 - 0.5f);
            e2 += bc * crz2[i] * (bt2 - 0.5f);
        }
        const int j = n & 31;
        const int u = (((n >> 7) & 1) << 2) | (((n >> 6) & 1) << 1) | ((n >> 5) & 1);
        const int idx = u * 36 + j;
        float s, c;
        __sincosf(e1, &s, &c);  Tc1[idx] = c;  Ts1[idx] = s;
        __sincosf(e2, &s, &c);  Tc2[idx] = c;  Ts2[idx] = s;
    }
    __syncthreads();

    const int lane = t & 63;
    const int u = ((lane & 1) << 2) | (((lane >> 1) & 1) << 1) | ((lane >> 3) & 1);
    const int g = ((lane >> 3) & 6) | ((lane >> 2) & 1);   // lane bits 5,4 -> g2,g1; bit2 -> g0

    // shared RY params (VALU-idle budget; once per kernel)
    float rc1[8], rs1[8], rc2[8], rs2[8];
#pragma unroll
    for (int i = 0; i < 8; ++i) {
        __sincosf(0.5f * ry1[i], &rs1[i], &rc1[i]);
        __sincosf(0.5f * ry2[i], &rs2[i], &rc2[i]);
    }

    const float* pc1 = &Tc1[u * 36];
    const float* ps1 = &Ts1[u * 36];
    const float* pc2 = &Tc2[u * 36];
    const float* ps2 = &Ts2[u * 36];

    const int wavesPerBlock = blockDim.x >> 6;
    const int gwave = blockIdx.x * wavesPerBlock + (t >> 6);

    const int b  = gwave * 8 + g;
    const int bl = (b < B) ? b : (B - 1);

    // ---- encoding: this item's 8 angles
    const float4* xp = (const float4*)(x + (size_t)bl * NW);
    float4 xa = xp[0], xb = xp[1];
    float cs[8], sn[8];
    __sincosf(0.5f * xa.x, &sn[0], &cs[0]);
    __sincosf(0.5f * xa.y, &sn[1], &cs[1]);
    __sincosf(0.5f * xa.z, &sn[2], &cs[2]);
    __sincosf(0.5f * xa.w, &sn[3], &cs[3]);
    __sincosf(0.5f * xb.x, &sn[4], &cs[4]);
    __sincosf(0.5f * xb.y, &sn[5], &cs[5]);
    __sincosf(0.5f * xb.z, &sn[6], &cs[6]);
    __sincosf(0.5f * xb.w, &sn[7], &cs[7]);

    // cross-lane factor: wire0<->lane bit0, wire1<->bit1, wire2<->bit3
    float pcf = ((lane & 1) ? sn[0] : cs[0])
              * ((lane & 2) ? sn[1] : cs[1])
              * ((lane & 8) ? sn[2] : cs[2]);

    // in-lane outer product: j bit4->wire3 ... bit0->wire7
    float t2[2], t4[4], t8[8], t16[16], a[32];
    t2[0] = pcf * cs[3];  t2[1] = pcf * sn[3];
#pragma unroll
    for (int k = 0; k < 2; ++k)  { t4[2*k]  = t2[k]  * cs[4];  t4[2*k+1]  = t2[k]  * sn[4]; }
#pragma unroll
    for (int k = 0; k < 4; ++k)  { t8[2*k]  = t4[k]  * cs[5];  t8[2*k+1]  = t4[k]  * sn[5]; }
#pragma unroll
    for (int k = 0; k < 8; ++k)  { t16[2*k] = t8[k]  * cs[6];  t16[2*k+1] = t8[k]  * sn[6]; }
#pragma unroll
    for (int k = 0; k < 16; ++k) { a[2*k]   = t16[k] * cs[7];  a[2*k+1]   = t16[k] * sn[7]; }

    // ---- CRZ block 1 on real state: re = a*cos, im = a*sin
    float re[32], im[32];
#pragma unroll
    for (int q = 0; q < 8; ++q) {
        float4 cq = *(const float4*)&pc1[4 * q];
        float4 sq = *(const float4*)&ps1[4 * q];
        re[4*q+0] = a[4*q+0] * cq.x;  im[4*q+0] = a[4*q+0] * sq.x;
        re[4*q+1] = a[4*q+1] * cq.y;  im[4*q+1] = a[4*q+1] * sq.y;
        re[4*q+2] = a[4*q+2] * cq.z;  im[4*q+2] = a[4*q+2] * sq.z;
        re[4*q+3] = a[4*q+3] * cq.w;  im[4*q+3] = a[4*q+3] * sq.w;
    }

#define CROSS_WIRE(RC, RS, WI, LBIT, EXCH)                                  \
    { float c = RC[WI], s = RS[WI];                                         \
      float se = (lane & LBIT) ? s : -s;                                    \
      _Pragma("unroll")                                                     \
      for (int j = 0; j < 32; ++j) {                                        \
          float pre = EXCH(re[j]);                                          \
          float pim = EXCH(im[j]);                                          \
          re[j] = fmaf(se, pre, c * re[j]);                                 \
          im[j] = fmaf(se, pim, c * im[j]);                                 \
      } }

#define INLANE_WIRE(RC, RS, WI, M)                                          \
    { float c = RC[WI], s = RS[WI];                                         \
      _Pragma("unroll")                                                     \
      for (int j = 0; j < 32; ++j) if (!(j & M)) {                          \
          int hi = j | M;                                                   \
          float rl = re[j], rh = re[hi], il = im[j], ih = im[hi];           \
          re[j]  = c * rl - s * rh;  re[hi] = fmaf(s, rl, c * rh);          \
          im[j]  = c * il - s * ih;  im[hi] = fmaf(s, il, c * ih);          \
      } }

#define RY_LAYER(RC, RS)                                                    \
    do {                                                                    \
        CROSS_WIRE(RC, RS, 0, 1, XCH1);                                     \
        CROSS_WIRE(RC, RS, 1, 2, XCH2);                                     \
        CROSS_WIRE(RC, RS, 2, 8, XCH8);                                     \
        INLANE_WIRE(RC, RS, 3, 16);                                         \
        INLANE_WIRE(RC, RS, 4, 8);                                          \
        INLANE_WIRE(RC, RS, 5, 4);                                          \
        INLANE_WIRE(RC, RS, 6, 2);                                          \
        INLANE_WIRE(RC, RS, 7, 1);                                          \
    } while (0)

    // ---- RY layer 1
    RY_LAYER(rc1, rs1);

    // ---- CRZ block 2: complex multiply
#pragma unroll
    for (int q = 0; q < 8; ++q) {
        float4 cq = *(const float4*)&pc2[4 * q];
        float4 sq = *(const float4*)&ps2[4 * q];
        float nr, ni;
        nr = re[4*q+0]*cq.x - im[4*q+0]*sq.x; ni = re[4*q+0]*sq.x + im[4*q+0]*cq.x; re[4*q+0] = nr; im[4*q+0] = ni;
        nr = re[4*q+1]*cq.y - im[4*q+1]*sq.y; ni = re[4*q+1]*sq.y + im[4*q+1]*cq.y; re[4*q+1] = nr; im[4*q+1] = ni;
        nr = re[4*q+2]*cq.z - im[4*q+2]*sq.z; ni = re[4*q+2]*sq.z + im[4*q+2]*cq.z; re[4*q+2] = nr; im[4*q+2] = ni;
        nr = re[4*q+3]*cq.w - im[4*q+3]*sq.w; ni = re[4*q+3]*sq.w + im[4*q+3]*cq.w; re[4*q+3] = nr; im[4*q+3] = ni;
    }

    // ---- RY layer 2
    RY_LAYER(rc2, rs2);

    // ---- probabilities + in-lane Walsh partials over j bits
    float p[32];
#pragma unroll
    for (int j = 0; j < 32; ++j) p[j] = re[j]*re[j] + im[j]*im[j];

    float s2_[16], d7 = 0.f;
#pragma unroll
    for (int k = 0; k < 16; ++k) { s2_[k] = p[2*k] + p[2*k+1]; d7 += p[2*k] - p[2*k+1]; }
    float s4_[8], d6 = 0.f;
#pragma unroll
    for (int k = 0; k < 8; ++k)  { s4_[k] = s2_[2*k] + s2_[2*k+1]; d6 += s2_[2*k] - s2_[2*k+1]; }
    float s8_[4], d5 = 0.f;
#pragma unroll
    for (int k = 0; k < 4; ++k)  { s8_[k] = s4_[2*k] + s4_[2*k+1]; d5 += s4_[2*k] - s4_[2*k+1]; }
    float s16a = s8_[0] + s8_[1], s16b = s8_[2] + s8_[3];
    float d4 = (s8_[0] - s8_[1]) + (s8_[2] - s8_[3]);
    float d3 = s16a - s16b;
    float v0 = s16a + s16b;

    // ---- cross-lane Walsh butterfly on lane bits {0,1,3}
#define BFLY_R(EXCH, M)                                                     \
    { float o0 = EXCH(v0), o3 = EXCH(d3), o4 = EXCH(d4),                    \
            o5 = EXCH(d5), o6 = EXCH(d6), o7 = EXCH(d7);                    \
      if (lane & M) { v0 = o0 - v0; d3 = o3 - d3; d4 = o4 - d4;             \
                      d5 = o5 - d5; d6 = o6 - d6; d7 = o7 - d7; }           \
      else          { v0 = o0 + v0; d3 = o3 + d3; d4 = o4 + d4;             \
                      d5 = o5 + d5; d6 = o6 + d6; d7 = o7 + d7; } }
    BFLY_R(XCH1, 1);
    BFLY_R(XCH2, 2);
    BFLY_R(XCH8, 8);
#undef BFLY_R

    // wire0 coeff at local lane (bits 0,1,3) == 1; wire1 == 2; wire2 == 8;
    // plain sums (wires 3..7) at local lane 0.
    if (b < B) {
        const int loc = lane & 11;
        float* ob = out + (size_t)b * NW;
        if      (loc == 0) { ob[3] = d3; *(float4*)(ob + 4) = make_float4(d4, d5, d6, d7); }
        else if (loc == 1) ob[0] = v0;
        else if (loc == 2) ob[1] = v0;
        else if (loc == 8) ob[2] = v0;
    }
#undef RY_LAYER
#undef CROSS_WIRE
#undef INLANE_WIRE
}

extern "C" void kernel_launch(void* const* d_in, const int* in_sizes, int n_in,
                              void* d_out, int out_size, void* d_ws, size_t ws_size,
                              hipStream_t stream) {
    const float* x    = (const float*)d_in[0];
    const float* ry1  = (const float*)d_in[1];
    const float* crz1 = (const float*)d_in[2];
    const float* ry2  = (const float*)d_in[3];
    const float* crz2 = (const float*)d_in[4];
    float* out = (float*)d_out;

    int B = in_sizes[0] / NW;                  // 16384
    // 8 items/wave, 4 waves/block -> 32 items/block
    int blocks = (B + 31) / 32;
    if (blocks < 1) blocks = 1;
    vqc_kernel<<<blocks, 256, 0, stream>>>(x, ry1, crz1, ry2, crz2, out, B);
}

// Round 5
// 68.966 us; speedup vs baseline: 1.3789x; 1.0120x over previous
//
#include <hip/hip_runtime.h>
#include <math.h>

#define NW 8

typedef float v2f __attribute__((ext_vector_type(2)));

__device__ __forceinline__ v2f mk2(float a, float b) { v2f r; r.x = a; r.y = b; return r; }

// ---- cross-lane exchanges: all DPP (VALU pipe, no DS) ----------------------
template<int CTRL>
__device__ __forceinline__ float dpp_x(float v) {
    return __int_as_float(
        __builtin_amdgcn_update_dpp(0, __float_as_int(v), CTRL, 0xF, 0xF, true));
}
template<int CTRL>
__device__ __forceinline__ v2f dpp2(v2f v) {
    v2f r;
    r.x = dpp_x<CTRL>(v.x);
    r.y = dpp_x<CTRL>(v.y);
    return r;
}
#define XCH1(v) dpp2<0xB1>(v)   /* quad_perm [1,0,3,2]  == lane XOR 1 */
#define XCH2(v) dpp2<0x4E>(v)   /* quad_perm [2,3,0,1]  == lane XOR 2 */
#define XCH8(v) dpp2<0x128>(v)  /* row_ror:8 on 16-rows == lane XOR 8 */

// Layout: wave = 8 items. Item id g = lane bits {5,4,2}; amplitude sublane
// u = lane bits {0,1,3}. Each lane holds 32 amplitudes n = (u0<<7)|(u1<<6)|
// (u2<<5)|j, packed as 16 float2 over j-pairs: vector index k = j>>1,
// j bit0 (wire7) = within-vector axis. k bit3->wire3 ... k bit0->wire6.
// Wires 0,1,2 cross-lane via DPP (XOR1/XOR2/XOR8 on lane bits 0,1,3).
__global__ __launch_bounds__(256, 2) void vqc_kernel(
    const float* __restrict__ x,     // [B,8]
    const float* __restrict__ ry1,   // [8]
    const float* __restrict__ crz1,  // [8]
    const float* __restrict__ ry2,   // [8]
    const float* __restrict__ crz2,  // [8]
    float* __restrict__ out,         // [B,8]
    int B)
{
    // CRZ tables: 8 rows (one per u) x 32 floats, padded to 36 so rows start
    // on disjoint bank quads; 144B rows keep 16B alignment for b128 reads.
    __shared__ __align__(16) float Tc1[288], Ts1[288], Tc2[288], Ts2[288];

    const int t = threadIdx.x;
    {
        const int n = t;  // basis index 0..255
        float e1 = 0.f, e2 = 0.f;
#pragma unroll
        for (int i = 0; i < NW; ++i) {
            float bc  = (float)((n >> (7 - i)) & 1);
            float bt1 = (float)((n >> (7 - ((i + 1) & 7))) & 1);
            float bt2 = (float)((n >> (7 - ((i + 7) & 7))) & 1);
            e1 += bc * crz1[i] * (bt1 - 0.5f);
            e2 += bc * crz2[i] * (bt2 - 0.5f);
        }
        const int j = n & 31;
        const int u = (((n >> 7) & 1) << 2) | (((n >> 6) & 1) << 1) | ((n >> 5) & 1);
        const int idx = u * 36 + j;
        float s, c;
        __sincosf(e1, &s, &c);  Tc1[idx] = c;  Ts1[idx] = s;
        __sincosf(e2, &s, &c);  Tc2[idx] = c;  Ts2[idx] = s;
    }
    __syncthreads();

    const int lane = t & 63;
    const int u = ((lane & 1) << 2) | (((lane >> 1) & 1) << 1) | ((lane >> 3) & 1);
    const int g = ((lane >> 3) & 6) | ((lane >> 2) & 1);

    // shared RY params (once per kernel)
    float rc1[8], rs1[8], rc2[8], rs2[8];
#pragma unroll
    for (int i = 0; i < 8; ++i) {
        __sincosf(0.5f * ry1[i], &rs1[i], &rc1[i]);
        __sincosf(0.5f * ry2[i], &rs2[i], &rc2[i]);
    }

    const float* pc1 = &Tc1[u * 36];
    const float* ps1 = &Ts1[u * 36];
    const float* pc2 = &Tc2[u * 36];
    const float* ps2 = &Ts2[u * 36];

    const int wavesPerBlock = blockDim.x >> 6;
    const int gwave = blockIdx.x * wavesPerBlock + (t >> 6);
    const int b  = gwave * 8 + g;
    const int bl = (b < B) ? b : (B - 1);

    // ---- encoding
    const float4* xp = (const float4*)(x + (size_t)bl * NW);
    float4 xa = xp[0], xb = xp[1];
    float cs[8], sn[8];
    __sincosf(0.5f * xa.x, &sn[0], &cs[0]);
    __sincosf(0.5f * xa.y, &sn[1], &cs[1]);
    __sincosf(0.5f * xa.z, &sn[2], &cs[2]);
    __sincosf(0.5f * xa.w, &sn[3], &cs[3]);
    __sincosf(0.5f * xb.x, &sn[4], &cs[4]);
    __sincosf(0.5f * xb.y, &sn[5], &cs[5]);
    __sincosf(0.5f * xb.z, &sn[6], &cs[6]);
    __sincosf(0.5f * xb.w, &sn[7], &cs[7]);

    // cross-lane factor: wire0<->lane bit0, wire1<->bit1, wire2<->bit3
    float pcf = ((lane & 1) ? sn[0] : cs[0])
              * ((lane & 2) ? sn[1] : cs[1])
              * ((lane & 8) ? sn[2] : cs[2]);

    // in-lane outer product over k bits (wire3<->k bit3 ... wire6<->k bit0),
    // then pack wire7 (within-vector) via {cs7, sn7}
    float t2[2], t4[4], t8[8], t16[16];
    t2[0] = pcf * cs[3];  t2[1] = pcf * sn[3];
#pragma unroll
    for (int k = 0; k < 2; ++k)  { t4[2*k]  = t2[k] * cs[4];  t4[2*k+1]  = t2[k] * sn[4]; }
#pragma unroll
    for (int k = 0; k < 4; ++k)  { t8[2*k]  = t4[k] * cs[5];  t8[2*k+1]  = t4[k] * sn[5]; }
#pragma unroll
    for (int k = 0; k < 8; ++k)  { t16[2*k] = t8[k] * cs[6];  t16[2*k+1] = t8[k] * sn[6]; }

    const v2f cw7 = mk2(cs[7], sn[7]);
    v2f aP[16];
#pragma unroll
    for (int k = 0; k < 16; ++k) aP[k] = mk2(t16[k], t16[k]) * cw7;

    // ---- CRZ block 1 on real state: re = a*cos, im = a*sin
    v2f reP[16], imP[16];
#pragma unroll
    for (int q = 0; q < 8; ++q) {
        float4 cq = *(const float4*)&pc1[4 * q];
        float4 sq = *(const float4*)&ps1[4 * q];
        v2f cl = mk2(cq.x, cq.y), ch = mk2(cq.z, cq.w);
        v2f sl = mk2(sq.x, sq.y), sh = mk2(sq.z, sq.w);
        reP[2*q]   = aP[2*q]   * cl;  imP[2*q]   = aP[2*q]   * sl;
        reP[2*q+1] = aP[2*q+1] * ch;  imP[2*q+1] = aP[2*q+1] * sh;
    }

#define CROSS_WIRE(RC, RS, WI, LBIT, EXCH)                                  \
    { float c_ = RC[WI], s_ = RS[WI];                                       \
      float se_ = (lane & LBIT) ? s_ : -s_;                                 \
      v2f cv = mk2(c_, c_), sev = mk2(se_, se_);                            \
      _Pragma("unroll")                                                     \
      for (int k = 0; k < 16; ++k) {                                        \
          v2f pre = EXCH(reP[k]);                                           \
          v2f pim = EXCH(imP[k]);                                           \
          reP[k] = reP[k] * cv + pre * sev;                                 \
          imP[k] = imP[k] * cv + pim * sev;                                 \
      } }

#define INLANE_WIRE(RC, RS, WI, M)                                          \
    { float c_ = RC[WI], s_ = RS[WI];                                       \
      v2f cv = mk2(c_, c_), sv = mk2(s_, s_);                               \
      _Pragma("unroll")                                                     \
      for (int k = 0; k < 16; ++k) if (!(k & M)) {                          \
          int h = k | M;                                                    \
          v2f rl = reP[k], rh = reP[h], il = imP[k], ih = imP[h];           \
          reP[k] = rl * cv - rh * sv;  reP[h] = rl * sv + rh * cv;          \
          imP[k] = il * cv - ih * sv;  imP[h] = il * sv + ih * cv;          \
      } }

#define WIRE7(RC, RS)                                                       \
    { float c_ = RC[7], s_ = RS[7];                                         \
      v2f cv = mk2(c_, c_), sev = mk2(-s_, s_);                             \
      _Pragma("unroll")                                                     \
      for (int k = 0; k < 16; ++k) {                                        \
          v2f r = reP[k], i = imP[k];                                       \
          v2f rsw = mk2(r.y, r.x), isw = mk2(i.y, i.x);                     \
          reP[k] = r * cv + rsw * sev;                                      \
          imP[k] = i * cv + isw * sev;                                      \
      } }

#define RY_LAYER(RC, RS)                                                    \
    do {                                                                    \
        CROSS_WIRE(RC, RS, 0, 1, XCH1);                                     \
        CROSS_WIRE(RC, RS, 1, 2, XCH2);                                     \
        CROSS_WIRE(RC, RS, 2, 8, XCH8);                                     \
        INLANE_WIRE(RC, RS, 3, 8);                                          \
        INLANE_WIRE(RC, RS, 4, 4);                                          \
        INLANE_WIRE(RC, RS, 5, 2);                                          \
        INLANE_WIRE(RC, RS, 6, 1);                                          \
        WIRE7(RC, RS);                                                      \
    } while (0)

    // ---- RY layer 1
    RY_LAYER(rc1, rs1);

    // ---- CRZ block 2: complex multiply
#pragma unroll
    for (int q = 0; q < 8; ++q) {
        float4 cq = *(const float4*)&pc2[4 * q];
        float4 sq = *(const float4*)&ps2[4 * q];
        v2f cl = mk2(cq.x, cq.y), ch = mk2(cq.z, cq.w);
        v2f sl = mk2(sq.x, sq.y), sh = mk2(sq.z, sq.w);
        v2f r, i;
        r = reP[2*q];   i = imP[2*q];
        reP[2*q]   = r * cl - i * sl;  imP[2*q]   = r * sl + i * cl;
        r = reP[2*q+1]; i = imP[2*q+1];
        reP[2*q+1] = r * ch - i * sh;  imP[2*q+1] = r * sh + i * ch;
    }

    // ---- RY layer 2
    RY_LAYER(rc2, rs2);

    // ---- probabilities (packed) + in-lane Walsh tree
    v2f pP[16];
#pragma unroll
    for (int k = 0; k < 16; ++k) pP[k] = reP[k] * reP[k] + imP[k] * imP[k];

    v2f s1v[8], dv6 = mk2(0.f, 0.f);
#pragma unroll
    for (int k = 0; k < 8; ++k) { s1v[k] = pP[2*k] + pP[2*k+1]; dv6 += pP[2*k] - pP[2*k+1]; }
    v2f s2v[4], dv5 = mk2(0.f, 0.f);
#pragma unroll
    for (int k = 0; k < 4; ++k) { s2v[k] = s1v[2*k] + s1v[2*k+1]; dv5 += s1v[2*k] - s1v[2*k+1]; }
    v2f s3v[2], dv4 = mk2(0.f, 0.f);
#pragma unroll
    for (int k = 0; k < 2; ++k) { s3v[k] = s2v[2*k] + s2v[2*k+1]; dv4 += s2v[2*k] - s2v[2*k+1]; }
    v2f sv0 = s3v[0] + s3v[1];
    v2f dv3 = s3v[0] - s3v[1];

    // within-vector axis is wire7
    float v0 = sv0.x + sv0.y, d7 = sv0.x - sv0.y;
    float d3 = dv3.x + dv3.y, d4 = dv4.x + dv4.y;
    float d5 = dv5.x + dv5.y, d6 = dv6.x + dv6.y;

    // ---- cross-lane Walsh butterfly on lane bits {0,1,3}, 3 packed values
    v2f w1 = mk2(v0, d3), w2 = mk2(d4, d5), w3 = mk2(d6, d7);
#define BFLY_R(EXCH, M)                                                     \
    { v2f o1 = EXCH(w1), o2 = EXCH(w2), o3 = EXCH(w3);                      \
      if (lane & M) { w1 = o1 - w1; w2 = o2 - w2; w3 = o3 - w3; }           \
      else          { w1 = o1 + w1; w2 = o2 + w2; w3 = o3 + w3; } }
    BFLY_R(XCH1, 1);
    BFLY_R(XCH2, 2);
    BFLY_R(XCH8, 8);
#undef BFLY_R

    // wire0 Walsh coeff at local lane (bits 0,1,3) == 1; wire1 == 2;
    // wire2 == 8; plain sums (wires 3..7) at local lane 0.
    if (b < B) {
        const int loc = lane & 11;
        float* ob = out + (size_t)b * NW;
        if      (loc == 0) { ob[3] = w1.y; *(float4*)(ob + 4) = make_float4(w2.x, w2.y, w3.x, w3.y); }
        else if (loc == 1) ob[0] = w1.x;
        else if (loc == 2) ob[1] = w1.x;
        else if (loc == 8) ob[2] = w1.x;
    }
#undef RY_LAYER
#undef CROSS_WIRE
#undef INLANE_WIRE
#undef WIRE7
}

extern "C" void kernel_launch(void* const* d_in, const int* in_sizes, int n_in,
                              void* d_out, int out_size, void* d_ws, size_t ws_size,
                              hipStream_t stream) {
    const float* x    = (const float*)d_in[0];
    const float* ry1  = (const float*)d_in[1];
    const float* crz1 = (const float*)d_in[2];
    const float* ry2  = (const float*)d_in[3];
    const float* crz2 = (const float*)d_in[4];
    float* out = (float*)d_out;

    int B = in_sizes[0] / NW;                  // 16384
    // 8 items/wave, 4 waves/block -> 32 items/block
    int blocks = (B + 31) / 32;
    if (blocks < 1) blocks = 1;
    vqc_kernel<<<blocks, 256, 0, stream>>>(x, ry1, crz1, ry2, crz2, out, B);
}